// Round 16
// baseline (79.985 us; speedup 1.0000x reference)
//
#include <hip/hip_runtime.h>

// MetricLoss: x[8192][128] f32 -> (loss_homo, loss_heter) f32.
// homo: exact per-group f32 algebra in prep (measured absmax 0.0).
// heter: persistent-pipeline bf16 32x32x16 MFMA Gram (R14 body, measured OK)
//        + fused final reduction via SPREAD atomics (R9 lesson applied):
//        16 accumulator cachelines (64 blocks each, parallel), 2-level spread
//        counters, vmcnt-ordered (NO __threadfence, NO same-line storm).
// R15 lesson: hipLaunchCooperativeKernel fails under this harness -> 2 plain
// dispatches, cross-kernel visibility via kernel-boundary flush (xb/sq/homo).

#define DIM   128
#define NBLK  1024
#define NPREP 512

typedef __bf16 bf16x8 __attribute__((ext_vector_type(8)));
typedef float  f32x16 __attribute__((ext_vector_type(16)));

__device__ __forceinline__ unsigned short f2bf(float f) {
  unsigned int u = __float_as_uint(f);
  u += 0x7fffu + ((u >> 16) & 1u);   // round-to-nearest-even
  return (unsigned short)(u >> 16);
}

__device__ __forceinline__ float wave_reduce(float v) {
#pragma unroll
  for (int off = 32; off > 0; off >>= 1) v += __shfl_xor(v, off);
  return v;
}

__device__ __forceinline__ void load_lds16(const void* g, void* l) {
  __builtin_amdgcn_global_load_lds(
      (const __attribute__((address_space(1))) void*)g,
      (__attribute__((address_space(3))) void*)l, 16, 0, 0);
}

// One wave per group of 4 rows. Phase A: norms + exact homo partial (lane=dim).
// Phase B: swizzled bf16 copy. Block 0 zeroes heter's spread atomics.
__global__ __launch_bounds__(256) void prep_kernel(
    const float* __restrict__ x, unsigned short* __restrict__ xb,
    float* __restrict__ sq, float* __restrict__ homo_part,
    float* __restrict__ acc, unsigned int* __restrict__ cnt1,
    unsigned int* __restrict__ cnt2) {
  if (blockIdx.x == 0) {
    if (threadIdx.x < 16) {                      // stride-32 = own 128B lines
      acc[threadIdx.x * 32] = 0.f;
      cnt1[threadIdx.x * 32] = 0u;
    }
    if (threadIdx.x == 16) *cnt2 = 0u;
  }
  const int wave = threadIdx.x >> 6;
  const int lane = threadIdx.x & 63;
  const int g = blockIdx.x * 4 + wave;           // 2048 groups
  float s0 = 0.f, s1 = 0.f, q = 0.f;
#pragma unroll
  for (int r = 0; r < 4; ++r) {
    const int row = g * 4 + r;
    const float v0 = x[row * DIM + lane];
    const float v1 = x[row * DIM + lane + 64];
    s0 += v0; s1 += v1;
    float rq = wave_reduce(v0 * v0 + v1 * v1);   // full row norm^2 (all lanes)
    if (lane == 0) sq[row] = rq;
    q += rq;
  }
  float ss = wave_reduce(s0 * s0 + s1 * s1);     // ||sum of 4 rows||^2
  __shared__ float hred[4];
  if (lane == 0) hred[wave] = 8.f * q - 2.f * ss;   // 2k*q - 2*ss, k=4

  const int r = lane >> 4, sl = lane & 15;
  const int row = g * 4 + r;
  const int c = sl ^ (row & 15);                 // source chunk for slot sl
  const float4* px = (const float4*)(x + row * DIM + c * 8);
  const float4 u0 = px[0], u1 = px[1];
  unsigned int p0 = (unsigned)f2bf(u0.x) | ((unsigned)f2bf(u0.y) << 16);
  unsigned int p1 = (unsigned)f2bf(u0.z) | ((unsigned)f2bf(u0.w) << 16);
  unsigned int p2 = (unsigned)f2bf(u1.x) | ((unsigned)f2bf(u1.y) << 16);
  unsigned int p3 = (unsigned)f2bf(u1.z) | ((unsigned)f2bf(u1.w) << 16);
  uint4 pk; pk.x = p0; pk.y = p1; pk.z = p2; pk.w = p3;
  *(uint4*)(xb + row * DIM + sl * 8) = pk;       // linear 16B store, coalesced

  __syncthreads();
  if (threadIdx.x == 0)
    homo_part[blockIdx.x] = hred[0] + hred[1] + hred[2] + hred[3];
}

// Persistent-pipeline heter (R14 body). Job j -> strip s, B-tile c.
// start(s) = s*(129-s). 4 waves: wave w owns rows 32w..32w+31 (A in regs).
__global__ __launch_bounds__(256, 4) void heter_kernel(
    const unsigned short* __restrict__ xb, const float* __restrict__ sq,
    const float* __restrict__ homo_part, float* __restrict__ acc,
    unsigned int* __restrict__ cnt1, unsigned int* __restrict__ cnt2,
    float* __restrict__ out) {
  __shared__ unsigned short Bl[2][64 * DIM];     // 2 x 16 KB

  const int wave = threadIdx.x >> 6;
  const int lane = threadIdx.x & 63;
  const int lc = lane & 31;                      // mfma row/col within 32
  const int lk = lane >> 5;                      // k-half selector
  const int sl = lc & 15;                        // swizzle key (rows 16-aligned)

  // Job range: XCD x gets contiguous 520 jobs; 128 blocks per XCD.
  const int xcd = blockIdx.x & 7, u = blockIdx.x >> 3;
  int j = xcd * 520 + 4 * u + min(u, 8);
  const int jend = j + ((u < 8) ? 5 : 4);

  // Decode first job -> (s, c).
  int s = (int)((129.0f - sqrtf(16641.0f - 4.0f * (float)j)) * 0.5f);
  s = min(max(s, 0), 63);
  while ((s + 1) * (129 - (s + 1)) <= j) ++s;
  while (s * (129 - s) > j) --s;
  int c = j - s * (129 - s);

  // A-slice of strip s into regs: rows 128s+32w+lc, all K (swizzled chunks).
  bf16x8 a[8];
  {
    const unsigned short* pA = xb + (128 * s + 32 * wave + lc) * DIM;
#pragma unroll
    for (int ks = 0; ks < 8; ++ks)
      a[ks] = *(const bf16x8*)(pA + (((2 * ks + lk) ^ sl) << 3));
  }

  // Prologue: stage first B-tile into buf 0.
  {
    const unsigned short* g = xb + (128 * s + 64 * c) * DIM;
#pragma unroll
    for (int i = 0; i < 4; ++i) {
      const int e = (wave * 16 + i * 4) * DIM;   // 4 rows (1 KB) per instr
      load_lds16(g + e + lane * 8, &Bl[0][e]);
    }
  }

  int buf = 0;
  float hs = 0.f;
  while (j < jend) {
    __syncthreads();                             // stage(buf) done; buf^1 free

    const int nj = j + 1;
    int ns = s, nc = c + 1;
    const bool havenext = (nj < jend);
    if (havenext) {
      if (nc >= 128 - 2 * ns) { ++ns; nc = 0; }  // strips all non-empty
      const unsigned short* g = xb + (128 * ns + 64 * nc) * DIM;
#pragma unroll
      for (int i = 0; i < 4; ++i) {
        const int e = (wave * 16 + i * 4) * DIM;
        load_lds16(g + e + lane * 8, &Bl[buf ^ 1][e]);
      }
    }

    // Compute current job from Bl[buf] with A regs.
    const unsigned short* bl = &Bl[buf][0];
    f32x16 acc0, acc1;
#pragma unroll
    for (int v = 0; v < 16; ++v) { acc0[v] = 0.f; acc1[v] = 0.f; }
#pragma unroll
    for (int ks = 0; ks < 8; ++ks) {
      const int so = (((2 * ks + lk) ^ sl) << 3);
      bf16x8 vb0 = *(const bf16x8*)&bl[(lc) * DIM + so];
      bf16x8 vb1 = *(const bf16x8*)&bl[(32 + lc) * DIM + so];
      acc0 = __builtin_amdgcn_mfma_f32_32x32x16_bf16(a[ks], vb0, acc0, 0, 0, 0);
      acc1 = __builtin_amdgcn_mfma_f32_32x32x16_bf16(a[ks], vb1, acc1, 0, 0, 0);
    }

    // Hinge epilogue (frag-level masking; groups 4-aligned, frags 32-aligned).
    {
      const int fr = 32 * wave;
      const int cb = 128 * s + 64 * c;           // global col base
      const int rb = 128 * s + fr;               // global row base (this wave)
      const bool up0 = (64 * c >= fr), dg0 = (64 * c == fr);
      const bool up1 = (64 * c + 32 >= fr), dg1 = (64 * c + 32 == fr);
      const float cj0 = 1.f - sq[cb + lc];
      const float cj1 = 1.f - sq[cb + 32 + lc];
      const int jg0 = (cb + lc) >> 2, jg1 = (cb + 32 + lc) >> 2;
#pragma unroll
      for (int r = 0; r < 16; ++r) {
        const int io = (r & 3) + 8 * (r >> 2) + 4 * lk;  // C/D row offset
        const int i = rb + io;
        const int ig = i >> 2;
        const float si = sq[i];
        if (up0) {
          float h = fmaxf(fmaf(2.f, acc0[r], cj0 - si), 0.f);
          if (dg0 && !(ig < jg0)) h = 0.f;
          hs += h;
        }
        if (up1) {
          float h = fmaxf(fmaf(2.f, acc1[r], cj1 - si), 0.f);
          if (dg1 && !(ig < jg1)) h = 0.f;
          hs += h;
        }
      }
    }

    // Roll state; reload A regs on strip change (L2-hot).
    if (havenext) {
      if (ns != s) {
        s = ns;
        const unsigned short* pA = xb + (128 * s + 32 * wave + lc) * DIM;
#pragma unroll
        for (int ks = 0; ks < 8; ++ks)
          a[ks] = *(const bf16x8*)(pA + (((2 * ks + lk) ^ sl) << 3));
      }
      c = nc;
      buf ^= 1;
    }
    j = nj;
  }

  // --- Fused tail: spread accumulators + 2-level spread counters ---
  hs = wave_reduce(hs);
  __shared__ float red[4];
  __shared__ int lastFlag;
  if (lane == 0) red[wave] = hs;
  if (threadIdx.x == 0) lastFlag = 0;
  __syncthreads();
  if (threadIdx.x == 0) {
    const float bs = red[0] + red[1] + red[2] + red[3];
    const int set = blockIdx.x & 15;             // 16 sets x 64 blocks
    atomicAdd(&acc[set * 32], bs);               // own 128B cacheline
    asm volatile("s_waitcnt vmcnt(0)" ::: "memory");  // order acc before ticket
    const unsigned int t1 = atomicAdd(&cnt1[set * 32], 1u);
    if (t1 == 63u) {                             // last of this set
      asm volatile("s_waitcnt vmcnt(0)" ::: "memory");
      const unsigned int t2 = atomicAdd(cnt2, 1u);
      if (t2 == 15u) lastFlag = 1;               // all acc adds complete
    }
  }
  __syncthreads();
  if (lastFlag) {
    float hmo = 0.f;
    for (int i = threadIdx.x; i < NPREP; i += 256) hmo += homo_part[i];
    hmo = wave_reduce(hmo);
    // lanes 0..15 of wave 0 read the 16 spread accs via RMW (coherence point)
    float s16 = 0.f;
    if (wave == 0 && lane < 16) s16 = atomicAdd(&acc[lane * 32], 0.0f);
    s16 = wave_reduce(s16);                      // wave 0: sum of 16 accs
    __shared__ float hred[4], sred;
    if (lane == 0) hred[wave] = hmo;
    if (threadIdx.x == 0) sred = s16;
    __syncthreads();
    if (threadIdx.x == 0) {
      out[0] = (hred[0] + hred[1] + hred[2] + hred[3]) / 24576.f;  // (B/k)*k*(k-1)
      out[1] = sred / 33538048.f;                                  // C(2048,2)*16
    }
  }
}

extern "C" void kernel_launch(void* const* d_in, const int* in_sizes, int n_in,
                              void* d_out, int out_size, void* d_ws, size_t ws_size,
                              hipStream_t stream) {
  const float* x = (const float*)d_in[0];
  float* out = (float*)d_out;
  char* ws = (char*)d_ws;
  // ws layout (bytes): [0] homo_part[512] (2 KB)
  //                    [4096] acc: 16 floats on own 128B lines (2 KB)
  //                    [6144] cnt1: 16 uints on own 128B lines (2 KB)
  //                    [8192] cnt2 (4 B)
  //                    [10496] sq[8192] (32 KB)
  //                    [43264] xb bf16[8192*128] swizzled (2 MB)
  float* homo_part    = (float*)(ws);
  float* acc          = (float*)(ws + 4096);
  unsigned int* cnt1  = (unsigned int*)(ws + 6144);
  unsigned int* cnt2  = (unsigned int*)(ws + 8192);
  float* sq           = (float*)(ws + 10496);
  unsigned short* xb  = (unsigned short*)(ws + 43264);

  hipLaunchKernelGGL(prep_kernel, dim3(NPREP), dim3(256), 0, stream,
                     x, xb, sq, homo_part, acc, cnt1, cnt2);
  hipLaunchKernelGGL(heter_kernel, dim3(NBLK), dim3(256), 0, stream,
                     xb, sq, homo_part, acc, cnt1, cnt2, out);
}